// Round 2
// baseline (165.971 us; speedup 1.0000x reference)
//
#include <hip/hip_runtime.h>

#define BSZ 64
#define SEQ 512
#define HD  768
#define TT  64          // topic/token list length
#define BPB 33          // blocks per batch: 1 cls + 16 topic + 16 token

// ---------------------------------------------------------------------------
// Fully-flat fused kernel: one launch, one task per wave.
// grid = 64 batches x 33 blocks = 2112 blocks x 256 threads (4 waves/block).
//   q==0    : cls task (wave 0 only; all waves help compute V rows 0,1)
//   q=1..16 : topic tasks l=(q-1)*4+wid  (V rows 2,3)
//   q=17..32: token tasks l=(q-17)*4+wid (V rows 4,5)
// Per block: stage dom[768] in LDS, compute the 2 effective-weight rows this
// block needs into LDS (V[o][m*8+c] = sum_a dom[m*8+a]*W[o][m*64+a*8+c]),
// then each wave does one task dot-product (hidden row global float4 x V LDS).
// LDS = 3 KB dom + 6 KB V = 9 KB -> ~8 blocks/CU -> 32 waves/CU (full occ),
// vs 2 blocks/CU (8 waves) in the previous 512-block version. Latency-bound
// gather loads now have 4x the TLP to hide under.
// ---------------------------------------------------------------------------
__global__ __launch_bounds__(256) void fused_kernel(
    const float* __restrict__ hidden,     // [64,512,768]
    const float* __restrict__ Wsrc,       // [862,384]
    const float* __restrict__ Wtgt,       // [862,384]
    const float* __restrict__ W_cls,      // [2,6144]
    const float* __restrict__ W_topic,    // [2,6144]
    const float* __restrict__ W_token,    // [2,6144]
    const float* __restrict__ b_cls,      // [2]
    const float* __restrict__ b_topic,    // [2]
    const float* __restrict__ b_token,    // [2]
    const int*   __restrict__ source_ids, // [64]
    const int*   __restrict__ target_ids, // [64]
    const int*   __restrict__ topic_inds, // [64,64]
    const float* __restrict__ topic_mask, // [64,64]
    const int*   __restrict__ token_inds, // [64,64]
    const float* __restrict__ token_mask, // [64,64]
    float*       __restrict__ out)        // [128 + 8192 + 8192]
{
    __shared__ __align__(16) float dom[HD];
    __shared__ __align__(16) float Vl[2][HD];   // 6 KB; +3 KB dom = 9 KB LDS

    const int blk = blockIdx.x;
    const int b   = blk / BPB;     // batch
    const int q   = blk - b * BPB; // 0=cls, 1..16=topic, 17..32=token
    const int tid = threadIdx.x;

    // ---- stage domain embedding -------------------------------------------
    const int sid = source_ids[b];
    const int tgt = target_ids[b];
    for (int j = tid; j < HD; j += 256)
        dom[j] = (j < 384) ? Wsrc[sid * 384 + j] : Wtgt[tgt * 384 + (j - 384)];
    __syncthreads();

    // ---- compute this block's 2 effective-weight rows into LDS ------------
    const float* Wp = (q == 0) ? W_cls : (q <= 16) ? W_topic : W_token;
    for (int idx = tid; idx < 2 * HD; idx += 256) {
        const int o = (idx >= HD) ? 1 : 0;
        const int d = idx - o * HD;
        const int m = d >> 3, c = d & 7;
        const float* wrow = Wp + o * 6144 + m * 64 + c;
        float acc = 0.f;
        #pragma unroll
        for (int a = 0; a < 8; ++a)
            acc = fmaf(dom[m * 8 + a], wrow[a * 8], acc);
        Vl[o][d] = acc;
    }
    __syncthreads();

    // ---- one task per wave ------------------------------------------------
    const int wid  = tid >> 6;
    const int lane = tid & 63;

    int pos, outoff;
    float mask;
    const float* bias;
    bool do_softmax;
    bool active = true;

    if (q == 0) {                                  // cls: wave 0 only
        active = (wid == 0);
        pos = 0; mask = 1.f; bias = b_cls; do_softmax = true;
        outoff = b * 2;
    } else if (q <= 16) {                          // topic
        const int l = (q - 1) * 4 + wid;
        pos = topic_inds[b * TT + l]; mask = topic_mask[b * TT + l];
        bias = b_topic; do_softmax = true;
        outoff = 128 + (b * TT + l) * 2;
    } else {                                       // token
        const int l = (q - 17) * 4 + wid;
        pos = token_inds[b * TT + l]; mask = token_mask[b * TT + l];
        bias = b_token; do_softmax = false;
        outoff = 128 + BSZ * TT * 2 + (b * TT + l) * 2;
    }

    if (active) {
        const float4* hrow = reinterpret_cast<const float4*>(
            hidden + ((size_t)b * SEQ + (size_t)pos) * HD);
        const float4* v0 = reinterpret_cast<const float4*>(&Vl[0][0]);
        const float4* v1 = reinterpret_cast<const float4*>(&Vl[1][0]);

        float a0 = 0.f, a1 = 0.f;
        #pragma unroll
        for (int k = 0; k < 3; ++k) {              // 768 floats = 64 lanes x 3 float4
            const float4 h4 = hrow[lane + k * 64];
            const float4 x0 = v0[lane + k * 64];
            const float4 x1 = v1[lane + k * 64];
            a0 = fmaf(h4.x, x0.x, a0); a1 = fmaf(h4.x, x1.x, a1);
            a0 = fmaf(h4.y, x0.y, a0); a1 = fmaf(h4.y, x1.y, a1);
            a0 = fmaf(h4.z, x0.z, a0); a1 = fmaf(h4.z, x1.z, a1);
            a0 = fmaf(h4.w, x0.w, a0); a1 = fmaf(h4.w, x1.w, a1);
        }
        #pragma unroll
        for (int off = 32; off > 0; off >>= 1) {
            a0 += __shfl_down(a0, off, 64);
            a1 += __shfl_down(a1, off, 64);
        }

        if (lane == 0) {
            const float l0 = fmaf(mask, a0, bias[0]);
            const float l1 = fmaf(mask, a1, bias[1]);
            if (do_softmax) {
                const float mx = fmaxf(l0, l1);
                const float e0 = __expf(l0 - mx);
                const float e1 = __expf(l1 - mx);
                const float inv = 1.f / (e0 + e1);
                out[outoff]     = e0 * inv;
                out[outoff + 1] = e1 * inv;
            } else {
                out[outoff]     = l0;
                out[outoff + 1] = l1;
            }
        }
    }
}

extern "C" void kernel_launch(void* const* d_in, const int* in_sizes, int n_in,
                              void* d_out, int out_size, void* d_ws, size_t ws_size,
                              hipStream_t stream) {
    const float* hidden     = (const float*)d_in[0];
    const float* Wsrc       = (const float*)d_in[1];
    const float* Wtgt       = (const float*)d_in[2];
    const float* W_cls      = (const float*)d_in[3];
    const float* b_cls      = (const float*)d_in[4];
    const float* W_topic    = (const float*)d_in[5];
    const float* b_topic    = (const float*)d_in[6];
    const float* W_token    = (const float*)d_in[7];
    const float* b_token    = (const float*)d_in[8];
    const int*   source_ids = (const int*)d_in[9];
    const int*   target_ids = (const int*)d_in[10];
    // d_in[11] ent_inds, d_in[12] ent_mask: dead in reference (never used)
    const int*   topic_inds = (const int*)d_in[13];
    const float* topic_mask = (const float*)d_in[14];
    const int*   token_inds = (const int*)d_in[15];
    const float* token_mask = (const float*)d_in[16];
    float* out = (float*)d_out;

    fused_kernel<<<BSZ * BPB, 256, 0, stream>>>(
        hidden, Wsrc, Wtgt, W_cls, W_topic, W_token,
        b_cls, b_topic, b_token, source_ids, target_ids,
        topic_inds, topic_mask, token_inds, token_mask, out);
}